// Round 6
// baseline (666.988 us; speedup 1.0000x reference)
//
#include <hip/hip_runtime.h>
#include <hip/hip_bf16.h>
#include <cstdint>

typedef unsigned short u16;
typedef short s16x8 __attribute__((ext_vector_type(8)));
typedef float f32x4 __attribute__((ext_vector_type(4)));

// 0.125 (1/sqrt(64)) * log2(e): folded into Q so QK^T yields s*log2e for exp2
#define QSCALE 0.18033688011112042f

#if __has_builtin(__builtin_amdgcn_exp2f)
#define EXP2(x) __builtin_amdgcn_exp2f(x)
#else
#define EXP2(x) __expf((x) * 0.6931471805599453f)
#endif

__device__ __forceinline__ u16 f2bf(float f) {
    union { float f; unsigned int u; } x; x.f = f;
    unsigned int r = (x.u + 0x7FFFu + ((x.u >> 16) & 1u)) >> 16;
    return (u16)r;
}

__device__ __forceinline__ unsigned fbits(float f) {
    union { float f; unsigned int u; } x; x.f = f;
    return x.u;
}

// cheap round-to-nearest (ties up) bf16 pack: (a -> lo16, b -> hi16)
__device__ __forceinline__ unsigned pack_bf2r(float a, float b) {
    return ((fbits(a) + 0x8000u) >> 16) | ((fbits(b) + 0x8000u) & 0xffff0000u);
}

// ---------------------------------------------------------------------------
// Batched weight convert: W fp32 [K][N] -> W^T bf16 [N][Kp], zero pad k>=K.
// ---------------------------------------------------------------------------
struct WPtrs { const float* s[8]; u16* d[8]; };

__global__ void wt_batch(WPtrs p, int K, int N, int Kp) {
    int idx = blockIdx.x * 256 + threadIdx.x;
    if (idx >= N * Kp) return;
    int n = idx / Kp, k = idx - n * Kp;
    const float* W = p.s[blockIdx.y];
    float v = (k < K) ? W[(size_t)k * N + n] : 0.f;
    p.d[blockIdx.y][idx] = f2bf(v);
}

// ---------------------------------------------------------------------------
// LayerNorm over 512, fp32 in -> bf16 out. One wave per row.
// ---------------------------------------------------------------------------
__global__ __launch_bounds__(256)
void ln512(const float* __restrict__ X, const float* __restrict__ g,
           const float* __restrict__ bta, u16* __restrict__ out) {
    const int lane = threadIdx.x & 63, w = threadIdx.x >> 6;
    const long row = (long)blockIdx.x * 4 + w;
    const float* xp = X + row * 512 + lane * 8;
    f32x4 a = *(const f32x4*)xp;
    f32x4 c = *(const f32x4*)(xp + 4);
    float s = 0.f, ss = 0.f;
#pragma unroll
    for (int i = 0; i < 4; i++) { s += a[i] + c[i]; ss += a[i]*a[i] + c[i]*c[i]; }
#pragma unroll
    for (int m = 1; m < 64; m <<= 1) { s += __shfl_xor(s, m); ss += __shfl_xor(ss, m); }
    float mean = s * (1.f / 512.f);
    float var  = ss * (1.f / 512.f) - mean * mean;
    float rs = rsqrtf(var + 1e-5f);
    f32x4 g0 = *(const f32x4*)(g + lane * 8);
    f32x4 g1 = *(const f32x4*)(g + lane * 8 + 4);
    f32x4 b0 = *(const f32x4*)(bta + lane * 8);
    f32x4 b1 = *(const f32x4*)(bta + lane * 8 + 4);
    s16x8 ov;
#pragma unroll
    for (int i = 0; i < 4; i++) {
        ov[i]     = (short)f2bf((a[i] - mean) * rs * g0[i] + b0[i]);
        ov[4 + i] = (short)f2bf((c[i] - mean) * rs * g1[i] + b1[i]);
    }
    *(s16x8*)&out[row * 512 + lane * 8] = ov;
}

// LayerNorm over 100 (Zelta), out padded to 128 cols bf16 (pad = 0)
__global__ __launch_bounds__(256)
void ln_z(const float* __restrict__ Z, const float* __restrict__ g,
          const float* __restrict__ bta, u16* __restrict__ out) {
    const int lane = threadIdx.x & 63, w = threadIdx.x >> 6;
    const long row = (long)blockIdx.x * 4 + w;
    const float* zp = Z + row * 100;
    float x0 = zp[lane];
    float x1 = (lane < 36) ? zp[64 + lane] : 0.f;
    float s = x0 + x1, ss = x0 * x0 + x1 * x1;
#pragma unroll
    for (int m = 1; m < 64; m <<= 1) { s += __shfl_xor(s, m); ss += __shfl_xor(ss, m); }
    float mean = s * 0.01f;
    float var  = ss * 0.01f - mean * mean;
    float rs = rsqrtf(var + 1e-5f);
    out[row * 128 + lane] = f2bf((x0 - mean) * rs * g[lane] + bta[lane]);
    u16 hi = 0;
    if (lane < 36) hi = f2bf((x1 - mean) * rs * g[64 + lane] + bta[64 + lane]);
    out[row * 128 + 64 + lane] = hi;
}

// ---------------------------------------------------------------------------
// GEMM: C[M][N] = A[M][K](bf16) @ B (given as B^T bf16 [N][K]).
// Tile BM x BN, BK=32, 4 waves as 2x2 (wave tile BM/2 x BN/2).
// EPI 0: bf16 out. 1: bf16 gelu(acc+bias). 2: fp32 acc(+bias)+res.
// 3: bf16 acc*QSCALE. 4: fused QK split: gn<512 -> Outv (scaled, stride 512),
//    else -> Outv2 (stride 512). Split is block-uniform (BN=64 tiles).
// ---------------------------------------------------------------------------
template <int BM, int BN, int EPI>
__global__ __launch_bounds__(256)
void gemm_t(const u16* __restrict__ A, const u16* __restrict__ BT,
            void* __restrict__ Outv, void* __restrict__ Outv2,
            const float* __restrict__ bias, const float* __restrict__ res,
            int M, int N, int K) {
    __shared__ u16 Ash[BM * 32];
    __shared__ u16 Bsh[BN * 32];
    constexpr int MR = BM / 32;          // frags per wave in m
    constexpr int NR = BN / 32;          // frags per wave in n
    constexpr int ROUNDS = (BM + BN) / 64;
    const int tid = threadIdx.x;
    const int lane = tid & 63, w = tid >> 6;
    const int wm = w >> 1, wn = w & 1;
    const int lr = lane & 15, lg = lane >> 4;
    const int seg = lane & 3;
    const long m0 = (long)blockIdx.y * BM, n0 = (long)blockIdx.x * BN;

    f32x4 acc[MR][NR];
#pragma unroll
    for (int i = 0; i < MR; i++)
#pragma unroll
        for (int j = 0; j < NR; j++) { f32x4 z = {0.f, 0.f, 0.f, 0.f}; acc[i][j] = z; }

    const int ksteps = K >> 5;
    for (int kk = 0; kk < ksteps; ++kk) {
        const long k0 = (long)kk * 32;
        __syncthreads();  // previous tile's reads complete
#pragma unroll
        for (int rd = 0; rd < ROUNDS; rd++) {
            const int rbase = rd * 64 + w * 16;       // wave-uniform
            const int r = rbase + (lane >> 2);        // per-lane source row
            if (rbase < BM) {
                __builtin_amdgcn_global_load_lds(
                    (const __attribute__((address_space(1))) void*)(A + (m0 + r) * K + k0 + seg * 8),
                    (__attribute__((address_space(3))) void*)(&Ash[rbase * 32]), 16, 0, 0);
            } else {
                __builtin_amdgcn_global_load_lds(
                    (const __attribute__((address_space(1))) void*)(BT + (n0 + r - BM) * K + k0 + seg * 8),
                    (__attribute__((address_space(3))) void*)(&Bsh[(rbase - BM) * 32]), 16, 0, 0);
            }
        }
        __syncthreads();  // barrier drains vmcnt -> LDS tile ready
        s16x8 af[MR], bf[NR];
#pragma unroll
        for (int mi = 0; mi < MR; mi++)
            af[mi] = *(const s16x8*)&Ash[(wm * (BM / 2) + mi * 16 + lr) * 32 + lg * 8];
#pragma unroll
        for (int ni = 0; ni < NR; ni++)
            bf[ni] = *(const s16x8*)&Bsh[(wn * (BN / 2) + ni * 16 + lr) * 32 + lg * 8];
#pragma unroll
        for (int mi = 0; mi < MR; mi++)
#pragma unroll
            for (int ni = 0; ni < NR; ni++)
                acc[mi][ni] = __builtin_amdgcn_mfma_f32_16x16x32_bf16(af[mi], bf[ni], acc[mi][ni], 0, 0, 0);
    }
    // epilogue: D layout: m = 4*(lane>>4)+reg, n = lane&15
#pragma unroll
    for (int mi = 0; mi < MR; mi++) {
#pragma unroll
        for (int ni = 0; ni < NR; ni++) {
#pragma unroll
            for (int r = 0; r < 4; r++) {
                long gm = m0 + wm * (BM / 2) + mi * 16 + lg * 4 + r;
                long gn = n0 + wn * (BN / 2) + ni * 16 + lr;
                float v = acc[mi][ni][r];
                if constexpr (EPI == 1) {
                    v += bias[gn];
                    v = 0.5f * v * (1.f + erff(v * 0.70710678118654752f));
                    ((u16*)Outv)[gm * (long)N + gn] = f2bf(v);
                } else if constexpr (EPI == 2) {
                    if (bias) v += bias[gn];
                    v += res[gm * (long)N + gn];
                    ((float*)Outv)[gm * (long)N + gn] = v;
                } else if constexpr (EPI == 3) {
                    ((u16*)Outv)[gm * (long)N + gn] = f2bf(v * QSCALE);
                } else if constexpr (EPI == 4) {
                    if (gn < 512) ((u16*)Outv)[gm * 512 + gn] = f2bf(v * QSCALE);
                    else          ((u16*)Outv2)[gm * 512 + (gn - 512)] = f2bf(v);
                } else {
                    ((u16*)Outv)[gm * (long)N + gn] = f2bf(v);
                }
            }
        }
    }
}

// ---------------------------------------------------------------------------
// Gated flash attention v4. 8 heads, d=64. Q pre-scaled by 0.125*log2e;
// fixed-max softmax: p = 2^st, gate st>0; per-lane psum, one reduce at end.
// 16 q-rows/wave, 4 waves/block, grid x = Lq/64 -> 1024 blocks (4 blk/CU,
// 4 waves/SIMD with launch_bounds cap). Register double-buffer (unroll 2),
// pointer-walk addressing. K row-major [tok][512]; V pre-transposed
// [512][Tk]. No barriers.
// ---------------------------------------------------------------------------
__global__ __launch_bounds__(256, 4)
void attn_gated4(const u16* __restrict__ Q, const u16* __restrict__ Kp,
                 const u16* __restrict__ VT, u16* __restrict__ O,
                 int Lq, int Lk, int Tk) {
    __shared__ u16 Psh[4][16 * 40];
    const int tid = threadIdx.x, lane = tid & 63, w = tid >> 6;
    const int lr = lane & 15, lg = lane >> 4;
    const int b = blockIdx.y >> 3, h = blockIdx.y & 7;
    const long qrow0 = (long)b * Lq + (long)blockIdx.x * 64 + w * 16;
    const int hoff = h * 64;

    s16x8 qf[2];
#pragma unroll
    for (int dc = 0; dc < 2; dc++)
        qf[dc] = *(const s16x8*)&Q[(qrow0 + lr) * 512 + hoff + dc * 32 + lg * 8];

    f32x4 o[4];
#pragma unroll
    for (int dt = 0; dt < 4; dt++) { f32x4 z = {0.f, 0.f, 0.f, 0.f}; o[dt] = z; }
    float psum = 0.f;

    const u16* pK = Kp + ((long)b * Lk) * 512 + hoff;
    const u16* pV = VT + (long)hoff * Tk + (long)b * Lk;
    int koff[2][2], voff[4];
#pragma unroll
    for (int c = 0; c < 2; c++)
#pragma unroll
        for (int dc = 0; dc < 2; dc++)
            koff[c][dc] = (c * 16 + lr) * 512 + dc * 32 + lg * 8;
#pragma unroll
    for (int dt = 0; dt < 4; dt++)
        voff[dt] = (dt * 16 + lr) * Tk + lg * 8;

    auto loadK = [&](s16x8 (&kf)[2][2], const u16* base) {
#pragma unroll
        for (int c = 0; c < 2; c++)
#pragma unroll
            for (int dc = 0; dc < 2; dc++)
                kf[c][dc] = *(const s16x8*)(base + koff[c][dc]);
    };
    auto loadV = [&](s16x8 (&vb)[4], const u16* base) {
#pragma unroll
        for (int dt = 0; dt < 4; dt++)
            vb[dt] = *(const s16x8*)(base + voff[dt]);
    };
    auto step = [&](const s16x8 (&kf)[2][2], const s16x8 (&vb)[4]) {
        f32x4 st[2];
        { f32x4 z = {0.f, 0.f, 0.f, 0.f}; st[0] = z; st[1] = z; }
#pragma unroll
        for (int c = 0; c < 2; c++)
#pragma unroll
            for (int dc = 0; dc < 2; dc++)
                st[c] = __builtin_amdgcn_mfma_f32_16x16x32_bf16(kf[c][dc], qf[dc], st[c], 0, 0, 0);
        // lane holds st = s*log2e for [k = c*16+4*lg+r][q = lr]
        uint2 pk[2];
#pragma unroll
        for (int c = 0; c < 2; c++) {
            float e0 = EXP2(st[c][0]), e1 = EXP2(st[c][1]);
            float e2 = EXP2(st[c][2]), e3 = EXP2(st[c][3]);
            psum += (e0 + e1) + (e2 + e3);
            float g0 = st[c][0] > 0.f ? e0 : 0.f;
            float g1 = st[c][1] > 0.f ? e1 : 0.f;
            float g2 = st[c][2] > 0.f ? e2 : 0.f;
            float g3 = st[c][3] > 0.f ? e3 : 0.f;
            pk[c].x = pack_bf2r(g0, g1);
            pk[c].y = pack_bf2r(g2, g3);
        }
        u16* psh = Psh[w];
#pragma unroll
        for (int c = 0; c < 2; c++)
            *(uint2*)&psh[lr * 40 + c * 16 + lg * 4] = pk[c];
        s16x8 pa = *(const s16x8*)&psh[lr * 40 + lg * 8];
#pragma unroll
        for (int dt = 0; dt < 4; dt++)
            o[dt] = __builtin_amdgcn_mfma_f32_16x16x32_bf16(pa, vb[dt], o[dt], 0, 0, 0);
    };

    s16x8 kfA[2][2], vbA[4], kfB[2][2], vbB[4];
    loadK(kfA, pK); loadV(vbA, pV);
    for (int kv0 = 0; kv0 < Lk; kv0 += 64) {
        loadK(kfB, pK + 32 * 512); loadV(vbB, pV + 32);
        step(kfA, vbA);
        pK += 64 * 512; pV += 64;
        if (kv0 + 64 < Lk) { loadK(kfA, pK); loadV(vbA, pV); }
        step(kfB, vbB);
    }

    float red = psum;
    red += __shfl_xor(red, 16);
    red += __shfl_xor(red, 32);
    float li0 = 1.f / __shfl(red, lg * 4 + 0), li1 = 1.f / __shfl(red, lg * 4 + 1);
    float li2 = 1.f / __shfl(red, lg * 4 + 2), li3 = 1.f / __shfl(red, lg * 4 + 3);
#pragma unroll
    for (int dt = 0; dt < 4; dt++) {
        long ob = qrow0 * 512 + hoff + dt * 16 + lr;
        O[ob + (long)(lg * 4 + 0) * 512] = f2bf(o[dt][0] * li0);
        O[ob + (long)(lg * 4 + 1) * 512] = f2bf(o[dt][1] * li1);
        O[ob + (long)(lg * 4 + 2) * 512] = f2bf(o[dt][2] * li2);
        O[ob + (long)(lg * 4 + 3) * 512] = f2bf(o[dt][3] * li3);
    }
}

// ---------------------------------------------------------------------------
extern "C" void kernel_launch(void* const* d_in, const int* in_sizes, int n_in,
                              void* d_out, int out_size, void* d_ws, size_t ws_size,
                              hipStream_t stream) {
    const float* X    = (const float*)d_in[0];   // [4,2048,512]
    const float* Z    = (const float*)d_in[1];   // [4,1024,100]
    const float* Wq_s = (const float*)d_in[2];
    const float* Wk_s = (const float*)d_in[3];
    const float* Wv_s = (const float*)d_in[4];
    const float* Wo_s = (const float*)d_in[5];
    const float* Wq_c = (const float*)d_in[6];
    const float* Wk_c = (const float*)d_in[7];   // [100,512]
    const float* Wv_c = (const float*)d_in[8];   // [100,512]
    const float* Wo_c = (const float*)d_in[9];
    const float* g1   = (const float*)d_in[10];
    const float* b1   = (const float*)d_in[11];
    const float* g2   = (const float*)d_in[12];
    const float* b2   = (const float*)d_in[13];
    const float* W1   = (const float*)d_in[14];
    const float* bf1  = (const float*)d_in[15];
    const float* W2   = (const float*)d_in[16];
    const float* bf2  = (const float*)d_in[17];
    float* out = (float*)d_out;

    char* p = (char*)d_ws;
    auto take = [&](size_t n) { char* q = p; p += (n + 255) & ~(size_t)255; return q; };
    u16* WqkT = (u16*)take((size_t)2 * 512 * 512 * 2);  // WqsT | WksT contiguous
    u16* WqsT = WqkT;
    u16* WksT = WqkT + 512 * 512;
    u16* WvsT = (u16*)take(512 * 512 * 2);
    u16* WosT = (u16*)take(512 * 512 * 2);
    u16* WqcT = (u16*)take(512 * 512 * 2);
    u16* WocT = (u16*)take(512 * 512 * 2);
    u16* W1T  = (u16*)take(512 * 512 * 2);
    u16* W2T  = (u16*)take(512 * 512 * 2);
    u16* WkcT = (u16*)take(512 * 128 * 2);
    u16* WvcT = (u16*)take(512 * 128 * 2);
    u16* nbuf = (u16*)take((size_t)8192 * 512 * 2);
    u16* qbuf = (u16*)take((size_t)8192 * 512 * 2);
    u16* kbuf = (u16*)take((size_t)8192 * 512 * 2);
    u16* vtbuf = (u16*)take((size_t)8192 * 512 * 2);  // V^T [512][tokens]
    u16* abuf = (u16*)take((size_t)8192 * 512 * 2);
    u16* znb  = (u16*)take((size_t)4096 * 128 * 2);

    // weights -> bf16 transposed (2 batched launches)
    WPtrs w8{};
    w8.s[0] = Wq_s; w8.d[0] = WqsT;
    w8.s[1] = Wk_s; w8.d[1] = WksT;
    w8.s[2] = Wv_s; w8.d[2] = WvsT;
    w8.s[3] = Wo_s; w8.d[3] = WosT;
    w8.s[4] = Wq_c; w8.d[4] = WqcT;
    w8.s[5] = Wo_c; w8.d[5] = WocT;
    w8.s[6] = W1;   w8.d[6] = W1T;
    w8.s[7] = W2;   w8.d[7] = W2T;
    wt_batch<<<dim3(1024, 8), 256, 0, stream>>>(w8, 512, 512, 512);
    WPtrs w2{};
    w2.s[0] = Wk_c; w2.d[0] = WkcT;
    w2.s[1] = Wv_c; w2.d[1] = WvcT;
    wt_batch<<<dim3(256, 2), 256, 0, stream>>>(w2, 100, 512, 128);

    // stage 1: self attention (Q+K fused projection; V transposed via swap)
    ln512<<<2048, 256, 0, stream>>>(X, g1, b1, nbuf);
    gemm_t<128, 64, 4><<<dim3(16, 64), 256, 0, stream>>>(nbuf, WqkT, qbuf, kbuf, nullptr, nullptr, 8192, 1024, 512);
    gemm_t<64, 128, 0><<<dim3(64, 8), 256, 0, stream>>>(WvsT, nbuf, vtbuf, nullptr, nullptr, nullptr, 512, 8192, 512);
    attn_gated4<<<dim3(32, 32), 256, 0, stream>>>(qbuf, kbuf, vtbuf, abuf, 2048, 2048, 8192);
    gemm_t<128, 64, 2><<<dim3(8, 64), 256, 0, stream>>>(abuf, WosT, d_out, nullptr, nullptr, X, 8192, 512, 512);

    // stage 2: cross attention
    ln512<<<2048, 256, 0, stream>>>(out, g1, b1, nbuf);
    ln_z<<<1024, 256, 0, stream>>>(Z, g2, b2, znb);
    gemm_t<128, 64, 3><<<dim3(8, 64), 256, 0, stream>>>(nbuf, WqcT, qbuf, nullptr, nullptr, nullptr, 8192, 512, 512);
    gemm_t<128, 64, 0><<<dim3(8, 32), 256, 0, stream>>>(znb, WkcT, kbuf, nullptr, nullptr, nullptr, 4096, 512, 128);
    gemm_t<64, 128, 0><<<dim3(32, 8), 256, 0, stream>>>(WvcT, znb, vtbuf, nullptr, nullptr, nullptr, 512, 4096, 128);
    attn_gated4<<<dim3(32, 32), 256, 0, stream>>>(qbuf, kbuf, vtbuf, abuf, 2048, 1024, 4096);
    gemm_t<128, 64, 2><<<dim3(8, 64), 256, 0, stream>>>(abuf, WocT, d_out, nullptr, nullptr, out, 8192, 512, 512);

    // stage 3: FFN
    ln512<<<2048, 256, 0, stream>>>(out, g1, b1, nbuf);
    gemm_t<128, 64, 1><<<dim3(8, 64), 256, 0, stream>>>(nbuf, W1T, abuf, nullptr, bf1, nullptr, 8192, 512, 512);
    gemm_t<128, 64, 2><<<dim3(8, 64), 256, 0, stream>>>(abuf, W2T, d_out, nullptr, bf2, out, 8192, 512, 512);
}

// Round 7
// 513.807 us; speedup vs baseline: 1.2981x; 1.2981x over previous
//
#include <hip/hip_runtime.h>
#include <hip/hip_bf16.h>
#include <cstdint>

typedef unsigned short u16;
typedef short s16x8 __attribute__((ext_vector_type(8)));
typedef float f32x4 __attribute__((ext_vector_type(4)));

// 0.125 (1/sqrt(64)) * log2(e): folded into Q so QK^T yields s*log2e for exp2
#define QSCALE 0.18033688011112042f

#if __has_builtin(__builtin_amdgcn_exp2f)
#define EXP2(x) __builtin_amdgcn_exp2f(x)
#else
#define EXP2(x) __expf((x) * 0.6931471805599453f)
#endif

__device__ __forceinline__ u16 f2bf(float f) {
    union { float f; unsigned int u; } x; x.f = f;
    unsigned int r = (x.u + 0x7FFFu + ((x.u >> 16) & 1u)) >> 16;
    return (u16)r;
}

__device__ __forceinline__ float bf2f(u16 u) {
    union { unsigned int u; float f; } x; x.u = ((unsigned)u) << 16;
    return x.f;
}

__device__ __forceinline__ unsigned fbits(float f) {
    union { float f; unsigned int u; } x; x.f = f;
    return x.u;
}

// cheap round-to-nearest (ties up) bf16 pack: (a -> lo16, b -> hi16)
__device__ __forceinline__ unsigned pack_bf2r(float a, float b) {
    return ((fbits(a) + 0x8000u) >> 16) | ((fbits(b) + 0x8000u) & 0xffff0000u);
}

// ---------------------------------------------------------------------------
// Batched weight convert: W fp32 [K][N] -> W^T bf16 [N][Kp], zero pad k>=K.
// ---------------------------------------------------------------------------
struct WPtrs { const float* s[8]; u16* d[8]; };

__global__ void wt_batch(WPtrs p, int K, int N, int Kp) {
    int idx = blockIdx.x * 256 + threadIdx.x;
    if (idx >= N * Kp) return;
    int n = idx / Kp, k = idx - n * Kp;
    const float* W = p.s[blockIdx.y];
    float v = (k < K) ? W[(size_t)k * N + n] : 0.f;
    p.d[blockIdx.y][idx] = f2bf(v);
}

// ---------------------------------------------------------------------------
// LayerNorm over 512, fp32 in -> bf16 out. One wave per row.
// ---------------------------------------------------------------------------
__global__ __launch_bounds__(256)
void ln512(const float* __restrict__ X, const float* __restrict__ g,
           const float* __restrict__ bta, u16* __restrict__ out) {
    const int lane = threadIdx.x & 63, w = threadIdx.x >> 6;
    const long row = (long)blockIdx.x * 4 + w;
    const float* xp = X + row * 512 + lane * 8;
    f32x4 a = *(const f32x4*)xp;
    f32x4 c = *(const f32x4*)(xp + 4);
    float s = 0.f, ss = 0.f;
#pragma unroll
    for (int i = 0; i < 4; i++) { s += a[i] + c[i]; ss += a[i]*a[i] + c[i]*c[i]; }
#pragma unroll
    for (int m = 1; m < 64; m <<= 1) { s += __shfl_xor(s, m); ss += __shfl_xor(ss, m); }
    float mean = s * (1.f / 512.f);
    float var  = ss * (1.f / 512.f) - mean * mean;
    float rs = rsqrtf(var + 1e-5f);
    f32x4 g0 = *(const f32x4*)(g + lane * 8);
    f32x4 g1 = *(const f32x4*)(g + lane * 8 + 4);
    f32x4 b0 = *(const f32x4*)(bta + lane * 8);
    f32x4 b1 = *(const f32x4*)(bta + lane * 8 + 4);
    s16x8 ov;
#pragma unroll
    for (int i = 0; i < 4; i++) {
        ov[i]     = (short)f2bf((a[i] - mean) * rs * g0[i] + b0[i]);
        ov[4 + i] = (short)f2bf((c[i] - mean) * rs * g1[i] + b1[i]);
    }
    *(s16x8*)&out[row * 512 + lane * 8] = ov;
}

// LayerNorm over 100 (Zelta), out padded to 128 cols bf16 (pad = 0)
__global__ __launch_bounds__(256)
void ln_z(const float* __restrict__ Z, const float* __restrict__ g,
          const float* __restrict__ bta, u16* __restrict__ out) {
    const int lane = threadIdx.x & 63, w = threadIdx.x >> 6;
    const long row = (long)blockIdx.x * 4 + w;
    const float* zp = Z + row * 100;
    float x0 = zp[lane];
    float x1 = (lane < 36) ? zp[64 + lane] : 0.f;
    float s = x0 + x1, ss = x0 * x0 + x1 * x1;
#pragma unroll
    for (int m = 1; m < 64; m <<= 1) { s += __shfl_xor(s, m); ss += __shfl_xor(ss, m); }
    float mean = s * 0.01f;
    float var  = ss * 0.01f - mean * mean;
    float rs = rsqrtf(var + 1e-5f);
    out[row * 128 + lane] = f2bf((x0 - mean) * rs * g[lane] + bta[lane]);
    u16 hi = 0;
    if (lane < 36) hi = f2bf((x1 - mean) * rs * g[64 + lane] + bta[64 + lane]);
    out[row * 128 + 64 + lane] = hi;
}

// ---------------------------------------------------------------------------
// GEMM, 2-phase pipelined: C[M][N] = A[M][K](bf16) @ B (B^T bf16 [N][K]).
// Double-buffered LDS; issue next tile's global_load_lds BEFORE computing
// the current tile, single __syncthreads per K-step (vmcnt drains at it).
// Tile BM x BN, BK=32, 4 waves as 2x2.
// EPI 0: bf16. 1: bf16 gelu(acc+bias). 2: fp32 acc(+bias)+res.
// 3: bf16 acc*QSCALE. 4: fused QK split (gn<512 -> Outv scaled, else Outv2).
// ---------------------------------------------------------------------------
template <int BM, int BN, int EPI>
__global__ __launch_bounds__(256)
void gemm_p(const u16* __restrict__ A, const u16* __restrict__ BT,
            void* __restrict__ Outv, void* __restrict__ Outv2,
            const float* __restrict__ bias, const float* __restrict__ res,
            int M, int N, int K) {
    __shared__ u16 Ash[2][BM * 32];
    __shared__ u16 Bsh[2][BN * 32];
    constexpr int MR = BM / 32;
    constexpr int NR = BN / 32;
    constexpr int ROUNDS = (BM + BN) / 64;
    const int tid = threadIdx.x;
    const int lane = tid & 63, w = tid >> 6;
    const int wm = w >> 1, wn = w & 1;
    const int lr = lane & 15, lg = lane >> 4;
    const int seg = lane & 3;
    const long m0 = (long)blockIdx.y * BM, n0 = (long)blockIdx.x * BN;

    f32x4 acc[MR][NR];
#pragma unroll
    for (int i = 0; i < MR; i++)
#pragma unroll
        for (int j = 0; j < NR; j++) { f32x4 z = {0.f, 0.f, 0.f, 0.f}; acc[i][j] = z; }

    auto stage = [&](int buf, int kk) {
        const long k0 = (long)kk * 32;
#pragma unroll
        for (int rd = 0; rd < ROUNDS; rd++) {
            const int rbase = rd * 64 + w * 16;       // wave-uniform
            const int r = rbase + (lane >> 2);        // per-lane source row
            if (rbase < BM) {
                __builtin_amdgcn_global_load_lds(
                    (const __attribute__((address_space(1))) void*)(A + (m0 + r) * K + k0 + seg * 8),
                    (__attribute__((address_space(3))) void*)(&Ash[buf][rbase * 32]), 16, 0, 0);
            } else {
                __builtin_amdgcn_global_load_lds(
                    (const __attribute__((address_space(1))) void*)(BT + (n0 + r - BM) * K + k0 + seg * 8),
                    (__attribute__((address_space(3))) void*)(&Bsh[buf][(rbase - BM) * 32]), 16, 0, 0);
            }
        }
    };

    const int ksteps = K >> 5;
    stage(0, 0);
    __syncthreads();                    // drain prologue loads
    int cur = 0;
    for (int kk = 0; kk < ksteps; ++kk) {
        if (kk + 1 < ksteps) stage(cur ^ 1, kk + 1);  // loads fly during MFMA
        s16x8 af[MR], bf[NR];
#pragma unroll
        for (int mi = 0; mi < MR; mi++)
            af[mi] = *(const s16x8*)&Ash[cur][(wm * (BM / 2) + mi * 16 + lr) * 32 + lg * 8];
#pragma unroll
        for (int ni = 0; ni < NR; ni++)
            bf[ni] = *(const s16x8*)&Bsh[cur][(wn * (BN / 2) + ni * 16 + lr) * 32 + lg * 8];
#pragma unroll
        for (int mi = 0; mi < MR; mi++)
#pragma unroll
            for (int ni = 0; ni < NR; ni++)
                acc[mi][ni] = __builtin_amdgcn_mfma_f32_16x16x32_bf16(af[mi], bf[ni], acc[mi][ni], 0, 0, 0);
        __syncthreads();                // drains next tile's vmcnt + barrier
        cur ^= 1;
    }
    // epilogue: D layout: m = 4*(lane>>4)+reg, n = lane&15
#pragma unroll
    for (int mi = 0; mi < MR; mi++) {
#pragma unroll
        for (int ni = 0; ni < NR; ni++) {
#pragma unroll
            for (int r = 0; r < 4; r++) {
                long gm = m0 + wm * (BM / 2) + mi * 16 + lg * 4 + r;
                long gn = n0 + wn * (BN / 2) + ni * 16 + lr;
                float v = acc[mi][ni][r];
                if constexpr (EPI == 1) {
                    v += bias[gn];
                    v = 0.5f * v * (1.f + erff(v * 0.70710678118654752f));
                    ((u16*)Outv)[gm * (long)N + gn] = f2bf(v);
                } else if constexpr (EPI == 2) {
                    if (bias) v += bias[gn];
                    v += res[gm * (long)N + gn];
                    ((float*)Outv)[gm * (long)N + gn] = v;
                } else if constexpr (EPI == 3) {
                    ((u16*)Outv)[gm * (long)N + gn] = f2bf(v * QSCALE);
                } else if constexpr (EPI == 4) {
                    if (gn < 512) ((u16*)Outv)[gm * 512 + gn] = f2bf(v * QSCALE);
                    else          ((u16*)Outv2)[gm * 512 + (gn - 512)] = f2bf(v);
                } else {
                    ((u16*)Outv)[gm * (long)N + gn] = f2bf(v);
                }
            }
        }
    }
}

// ---------------------------------------------------------------------------
// Gated flash attention v5, KV-split. 8 heads, d=64. Q pre-scaled by
// 0.125*log2e; fixed-max softmax: p = 2^st, gate st>0.
// 32 q-rows/wave (2x16), 4 waves/block, blockIdx.z = KV half.
// Writes UNNORMALIZED bf16 O-part + per-(row,head) psum; combine kernel
// finishes. Bijective XCD swizzle keeps each XCD's KV working set ~4MB.
// ---------------------------------------------------------------------------
__global__ __launch_bounds__(256)
void attn_gated5(const u16* __restrict__ Q, const u16* __restrict__ Kp,
                 const u16* __restrict__ VT, u16* __restrict__ OP,
                 float* __restrict__ PS, int Lq, int Lk, int Tk, int TT) {
    __shared__ u16 Psh[4][2][16 * 40];
    const int tid = threadIdx.x, lane = tid & 63, w = tid >> 6;
    const int lr = lane & 15, lg = lane >> 4;

    // bijective XCD swizzle on flat block id (nwg = 1024, % 8 == 0)
    const int nx = gridDim.x, ny = gridDim.y;
    int id = blockIdx.x + nx * (blockIdx.y + ny * blockIdx.z);
    int qq = (nx * ny * gridDim.z) >> 3;
    int r2 = (id & 7) * qq + (id >> 3);
    int bx = r2 % nx; int t1 = r2 / nx; int by = t1 % ny; int bz = t1 / ny;

    const int b = by >> 3, h = by & 7;
    const long qrow0 = (long)b * Lq + (long)bx * 128 + w * 32;
    const int hoff = h * 64;
    const int Lkh = Lk >> 1;

    s16x8 qf[2][2];
#pragma unroll
    for (int s = 0; s < 2; s++)
#pragma unroll
        for (int dc = 0; dc < 2; dc++)
            qf[s][dc] = *(const s16x8*)&Q[(qrow0 + s * 16 + lr) * 512 + hoff + dc * 32 + lg * 8];

    f32x4 o[2][4];
#pragma unroll
    for (int s = 0; s < 2; s++)
#pragma unroll
        for (int dt = 0; dt < 4; dt++) { f32x4 z = {0.f, 0.f, 0.f, 0.f}; o[s][dt] = z; }
    float psum[2] = {0.f, 0.f};

    const u16* pK = Kp + ((long)b * Lk + (long)bz * Lkh) * 512 + hoff;
    const u16* pV = VT + (long)hoff * Tk + (long)b * Lk + (long)bz * Lkh;
    int koff[2][2], voff[4];
#pragma unroll
    for (int c = 0; c < 2; c++)
#pragma unroll
        for (int dc = 0; dc < 2; dc++)
            koff[c][dc] = (c * 16 + lr) * 512 + dc * 32 + lg * 8;
#pragma unroll
    for (int dt = 0; dt < 4; dt++)
        voff[dt] = (dt * 16 + lr) * Tk + lg * 8;

    for (int kv = 0; kv < Lkh; kv += 32) {
        s16x8 kf[2][2], vb[4];
#pragma unroll
        for (int c = 0; c < 2; c++)
#pragma unroll
            for (int dc = 0; dc < 2; dc++)
                kf[c][dc] = *(const s16x8*)(pK + koff[c][dc]);
#pragma unroll
        for (int dt = 0; dt < 4; dt++)
            vb[dt] = *(const s16x8*)(pV + voff[dt]);
#pragma unroll
        for (int s = 0; s < 2; s++) {
            f32x4 st[2];
            { f32x4 z = {0.f, 0.f, 0.f, 0.f}; st[0] = z; st[1] = z; }
#pragma unroll
            for (int c = 0; c < 2; c++)
#pragma unroll
                for (int dc = 0; dc < 2; dc++)
                    st[c] = __builtin_amdgcn_mfma_f32_16x16x32_bf16(kf[c][dc], qf[s][dc], st[c], 0, 0, 0);
            uint2 pk[2];
#pragma unroll
            for (int c = 0; c < 2; c++) {
                float e0 = EXP2(st[c][0]), e1 = EXP2(st[c][1]);
                float e2 = EXP2(st[c][2]), e3 = EXP2(st[c][3]);
                psum[s] += (e0 + e1) + (e2 + e3);
                float g0 = st[c][0] > 0.f ? e0 : 0.f;
                float g1 = st[c][1] > 0.f ? e1 : 0.f;
                float g2 = st[c][2] > 0.f ? e2 : 0.f;
                float g3 = st[c][3] > 0.f ? e3 : 0.f;
                pk[c].x = pack_bf2r(g0, g1);
                pk[c].y = pack_bf2r(g2, g3);
            }
            u16* psh = &Psh[w][s][0];
#pragma unroll
            for (int c = 0; c < 2; c++)
                *(uint2*)&psh[lr * 40 + c * 16 + lg * 4] = pk[c];
            s16x8 pa = *(const s16x8*)&psh[lr * 40 + lg * 8];
#pragma unroll
            for (int dt = 0; dt < 4; dt++)
                o[s][dt] = __builtin_amdgcn_mfma_f32_16x16x32_bf16(pa, vb[dt], o[s][dt], 0, 0, 0);
        }
        pK += 32 * 512; pV += 32;
    }

    u16* op = OP + (long)bz * TT * 512;
    float* ps = PS + (long)bz * TT * 8;
#pragma unroll
    for (int s = 0; s < 2; s++) {
        float red = psum[s];
        red += __shfl_xor(red, 16);
        red += __shfl_xor(red, 32);
        if (lg == 0) ps[(qrow0 + s * 16 + lr) * 8 + h] = red;
#pragma unroll
        for (int dt = 0; dt < 4; dt++) {
            long ob = (qrow0 + s * 16) * 512 + hoff + dt * 16 + lr;
            op[ob + (long)(lg * 4 + 0) * 512] = f2bf(o[s][dt][0]);
            op[ob + (long)(lg * 4 + 1) * 512] = f2bf(o[s][dt][1]);
            op[ob + (long)(lg * 4 + 2) * 512] = f2bf(o[s][dt][2]);
            op[ob + (long)(lg * 4 + 3) * 512] = f2bf(o[s][dt][3]);
        }
    }
}

// combine: O = (P0 + P1) / (ps0 + ps1), 8 dims per thread
__global__ __launch_bounds__(256)
void attn_combine(const u16* __restrict__ OP, const float* __restrict__ PS,
                  u16* __restrict__ O, int TT) {
    long i = (long)blockIdx.x * 256 + threadIdx.x;
    long t = i >> 6; int g = (int)(i & 63); int d0 = g * 8; int h = g >> 3;
    float rinv = 1.f / (PS[t * 8 + h] + PS[(long)TT * 8 + t * 8 + h]);
    s16x8 va = *(const s16x8*)&OP[t * 512 + d0];
    s16x8 vb = *(const s16x8*)&OP[(long)TT * 512 + t * 512 + d0];
    s16x8 ov;
#pragma unroll
    for (int j = 0; j < 8; j++)
        ov[j] = (short)f2bf((bf2f((u16)va[j]) + bf2f((u16)vb[j])) * rinv);
    *(s16x8*)&O[t * 512 + d0] = ov;
}

// ---------------------------------------------------------------------------
extern "C" void kernel_launch(void* const* d_in, const int* in_sizes, int n_in,
                              void* d_out, int out_size, void* d_ws, size_t ws_size,
                              hipStream_t stream) {
    const float* X    = (const float*)d_in[0];   // [4,2048,512]
    const float* Z    = (const float*)d_in[1];   // [4,1024,100]
    const float* Wq_s = (const float*)d_in[2];
    const float* Wk_s = (const float*)d_in[3];
    const float* Wv_s = (const float*)d_in[4];
    const float* Wo_s = (const float*)d_in[5];
    const float* Wq_c = (const float*)d_in[6];
    const float* Wk_c = (const float*)d_in[7];   // [100,512]
    const float* Wv_c = (const float*)d_in[8];   // [100,512]
    const float* Wo_c = (const float*)d_in[9];
    const float* g1   = (const float*)d_in[10];
    const float* b1   = (const float*)d_in[11];
    const float* g2   = (const float*)d_in[12];
    const float* b2   = (const float*)d_in[13];
    const float* W1   = (const float*)d_in[14];
    const float* bf1  = (const float*)d_in[15];
    const float* W2   = (const float*)d_in[16];
    const float* bf2  = (const float*)d_in[17];
    float* out = (float*)d_out;
    const int TT = 8192;  // total token rows (4 * 2048)

    char* p = (char*)d_ws;
    auto take = [&](size_t n) { char* q = p; p += (n + 255) & ~(size_t)255; return q; };
    u16* WqkT = (u16*)take((size_t)2 * 512 * 512 * 2);  // WqsT | WksT contiguous
    u16* WqsT = WqkT;
    u16* WksT = WqkT + 512 * 512;
    u16* WvsT = (u16*)take(512 * 512 * 2);
    u16* WosT = (u16*)take(512 * 512 * 2);
    u16* WqcT = (u16*)take(512 * 512 * 2);
    u16* WocT = (u16*)take(512 * 512 * 2);
    u16* W1T  = (u16*)take(512 * 512 * 2);
    u16* W2T  = (u16*)take(512 * 512 * 2);
    u16* WkcT = (u16*)take(512 * 128 * 2);
    u16* WvcT = (u16*)take(512 * 128 * 2);
    u16* nbuf = (u16*)take((size_t)TT * 512 * 2);
    u16* qbuf = (u16*)take((size_t)TT * 512 * 2);
    u16* kbuf = (u16*)take((size_t)TT * 512 * 2);
    u16* vtbuf = (u16*)take((size_t)TT * 512 * 2);   // V^T [512][tokens]
    u16* abuf = (u16*)take((size_t)TT * 512 * 2);
    u16* znb  = (u16*)take((size_t)4096 * 128 * 2);
    u16* opart = (u16*)take((size_t)2 * TT * 512 * 2);  // unnormalized O halves
    float* psum = (float*)take((size_t)2 * TT * 8 * 4); // softmax denominators

    // weights -> bf16 transposed (2 batched launches)
    WPtrs w8{};
    w8.s[0] = Wq_s; w8.d[0] = WqsT;
    w8.s[1] = Wk_s; w8.d[1] = WksT;
    w8.s[2] = Wv_s; w8.d[2] = WvsT;
    w8.s[3] = Wo_s; w8.d[3] = WosT;
    w8.s[4] = Wq_c; w8.d[4] = WqcT;
    w8.s[5] = Wo_c; w8.d[5] = WocT;
    w8.s[6] = W1;   w8.d[6] = W1T;
    w8.s[7] = W2;   w8.d[7] = W2T;
    wt_batch<<<dim3(1024, 8), 256, 0, stream>>>(w8, 512, 512, 512);
    WPtrs w2{};
    w2.s[0] = Wk_c; w2.d[0] = WkcT;
    w2.s[1] = Wv_c; w2.d[1] = WvcT;
    wt_batch<<<dim3(256, 2), 256, 0, stream>>>(w2, 100, 512, 128);

    // stage 1: self attention (Q+K fused projection; V transposed via swap)
    ln512<<<2048, 256, 0, stream>>>(X, g1, b1, nbuf);
    gemm_p<128, 64, 4><<<dim3(16, 64), 256, 0, stream>>>(nbuf, WqkT, qbuf, kbuf, nullptr, nullptr, 8192, 1024, 512);
    gemm_p<64, 128, 0><<<dim3(64, 8), 256, 0, stream>>>(WvsT, nbuf, vtbuf, nullptr, nullptr, nullptr, 512, 8192, 512);
    attn_gated5<<<dim3(16, 32, 2), 256, 0, stream>>>(qbuf, kbuf, vtbuf, opart, psum, 2048, 2048, 8192, TT);
    attn_combine<<<2048, 256, 0, stream>>>(opart, psum, abuf, TT);
    gemm_p<128, 64, 2><<<dim3(8, 64), 256, 0, stream>>>(abuf, WosT, d_out, nullptr, nullptr, X, 8192, 512, 512);

    // stage 2: cross attention
    ln512<<<2048, 256, 0, stream>>>(out, g1, b1, nbuf);
    ln_z<<<1024, 256, 0, stream>>>(Z, g2, b2, znb);
    gemm_p<128, 64, 3><<<dim3(8, 64), 256, 0, stream>>>(nbuf, WqcT, qbuf, nullptr, nullptr, nullptr, 8192, 512, 512);
    gemm_p<128, 64, 0><<<dim3(8, 32), 256, 0, stream>>>(znb, WkcT, kbuf, nullptr, nullptr, nullptr, 4096, 512, 128);
    gemm_p<64, 128, 0><<<dim3(32, 8), 256, 0, stream>>>(WvcT, znb, vtbuf, nullptr, nullptr, nullptr, 512, 4096, 128);
    attn_gated5<<<dim3(16, 32, 2), 256, 0, stream>>>(qbuf, kbuf, vtbuf, opart, psum, 2048, 1024, 4096, TT);
    attn_combine<<<2048, 256, 0, stream>>>(opart, psum, abuf, TT);
    gemm_p<128, 64, 2><<<dim3(8, 64), 256, 0, stream>>>(abuf, WocT, d_out, nullptr, nullptr, out, 8192, 512, 512);

    // stage 3: FFN
    ln512<<<2048, 256, 0, stream>>>(out, g1, b1, nbuf);
    gemm_p<128, 64, 1><<<dim3(8, 64), 256, 0, stream>>>(nbuf, W1T, abuf, nullptr, bf1, nullptr, 8192, 512, 512);
    gemm_p<128, 64, 2><<<dim3(8, 64), 256, 0, stream>>>(abuf, W2T, d_out, nullptr, bf2, out, 8192, 512, 512);
}

// Round 8
// 375.595 us; speedup vs baseline: 1.7758x; 1.3680x over previous
//
#include <hip/hip_runtime.h>
#include <hip/hip_bf16.h>
#include <cstdint>

typedef unsigned short u16;
typedef short s16x8 __attribute__((ext_vector_type(8)));
typedef float f32x4 __attribute__((ext_vector_type(4)));

#define AS1 __attribute__((address_space(1)))
#define AS3 __attribute__((address_space(3)))

// 0.125 (1/sqrt(64)) * log2(e): folded into Q so QK^T yields s*log2e for exp2
#define QSCALE 0.18033688011112042f

#if __has_builtin(__builtin_amdgcn_exp2f)
#define EXP2(x) __builtin_amdgcn_exp2f(x)
#else
#define EXP2(x) __expf((x) * 0.6931471805599453f)
#endif

__device__ __forceinline__ u16 f2bf(float f) {
    union { float f; unsigned int u; } x; x.f = f;
    unsigned int r = (x.u + 0x7FFFu + ((x.u >> 16) & 1u)) >> 16;
    return (u16)r;
}

__device__ __forceinline__ float bf2f(u16 u) {
    union { unsigned int u; float f; } x; x.u = ((unsigned)u) << 16;
    return x.f;
}

__device__ __forceinline__ unsigned fbits(float f) {
    union { float f; unsigned int u; } x; x.f = f;
    return x.u;
}

// cheap round-to-nearest (ties up) bf16 pack: (a -> lo16, b -> hi16)
__device__ __forceinline__ unsigned pack_bf2r(float a, float b) {
    return ((fbits(a) + 0x8000u) >> 16) | ((fbits(b) + 0x8000u) & 0xffff0000u);
}

// ---------------------------------------------------------------------------
// Batched weight convert: W fp32 [K][N] -> W^T bf16 [N][Kp], zero pad k>=K.
// ---------------------------------------------------------------------------
struct WPtrs { const float* s[8]; u16* d[8]; };

__global__ void wt_batch(WPtrs p, int K, int N, int Kp) {
    int idx = blockIdx.x * 256 + threadIdx.x;
    if (idx >= N * Kp) return;
    int n = idx / Kp, k = idx - n * Kp;
    const float* W = p.s[blockIdx.y];
    float v = (k < K) ? W[(size_t)k * N + n] : 0.f;
    p.d[blockIdx.y][idx] = f2bf(v);
}

// ---------------------------------------------------------------------------
// LayerNorm over 512, fp32 in -> bf16 out. One wave per row.
// ---------------------------------------------------------------------------
__global__ __launch_bounds__(256)
void ln512(const float* __restrict__ X, const float* __restrict__ g,
           const float* __restrict__ bta, u16* __restrict__ out) {
    const int lane = threadIdx.x & 63, w = threadIdx.x >> 6;
    const long row = (long)blockIdx.x * 4 + w;
    const float* xp = X + row * 512 + lane * 8;
    f32x4 a = *(const f32x4*)xp;
    f32x4 c = *(const f32x4*)(xp + 4);
    float s = 0.f, ss = 0.f;
#pragma unroll
    for (int i = 0; i < 4; i++) { s += a[i] + c[i]; ss += a[i]*a[i] + c[i]*c[i]; }
#pragma unroll
    for (int m = 1; m < 64; m <<= 1) { s += __shfl_xor(s, m); ss += __shfl_xor(ss, m); }
    float mean = s * (1.f / 512.f);
    float var  = ss * (1.f / 512.f) - mean * mean;
    float rs = rsqrtf(var + 1e-5f);
    f32x4 g0 = *(const f32x4*)(g + lane * 8);
    f32x4 g1 = *(const f32x4*)(g + lane * 8 + 4);
    f32x4 b0 = *(const f32x4*)(bta + lane * 8);
    f32x4 b1 = *(const f32x4*)(bta + lane * 8 + 4);
    s16x8 ov;
#pragma unroll
    for (int i = 0; i < 4; i++) {
        ov[i]     = (short)f2bf((a[i] - mean) * rs * g0[i] + b0[i]);
        ov[4 + i] = (short)f2bf((c[i] - mean) * rs * g1[i] + b1[i]);
    }
    *(s16x8*)&out[row * 512 + lane * 8] = ov;
}

// LayerNorm over 100 (Zelta), out padded to 128 cols bf16 (pad = 0)
__global__ __launch_bounds__(256)
void ln_z(const float* __restrict__ Z, const float* __restrict__ g,
          const float* __restrict__ bta, u16* __restrict__ out) {
    const int lane = threadIdx.x & 63, w = threadIdx.x >> 6;
    const long row = (long)blockIdx.x * 4 + w;
    const float* zp = Z + row * 100;
    float x0 = zp[lane];
    float x1 = (lane < 36) ? zp[64 + lane] : 0.f;
    float s = x0 + x1, ss = x0 * x0 + x1 * x1;
#pragma unroll
    for (int m = 1; m < 64; m <<= 1) { s += __shfl_xor(s, m); ss += __shfl_xor(ss, m); }
    float mean = s * 0.01f;
    float var  = ss * 0.01f - mean * mean;
    float rs = rsqrtf(var + 1e-5f);
    out[row * 128 + lane] = f2bf((x0 - mean) * rs * g[lane] + bta[lane]);
    u16 hi = 0;
    if (lane < 36) hi = f2bf((x1 - mean) * rs * g[64 + lane] + bta[64 + lane]);
    out[row * 128 + 64 + lane] = hi;
}

// ---------------------------------------------------------------------------
// GEMM, 2-phase pipelined: C[M][N] = A[M][K](bf16) @ B (B^T bf16 [N][K]).
// Double-buffered LDS; issue next tile's global_load_lds BEFORE computing
// the current tile, single __syncthreads per K-step.
// EPI 0: bf16. 1: bf16 gelu(acc+bias). 2: fp32 acc(+bias)+res.
// 3: bf16 acc*QSCALE. 4: fused QK split (gn<512 -> Outv scaled, else Outv2).
// ---------------------------------------------------------------------------
template <int BM, int BN, int EPI>
__global__ __launch_bounds__(256)
void gemm_p(const u16* __restrict__ A, const u16* __restrict__ BT,
            void* __restrict__ Outv, void* __restrict__ Outv2,
            const float* __restrict__ bias, const float* __restrict__ res,
            int M, int N, int K) {
    __shared__ u16 Ash[2][BM * 32];
    __shared__ u16 Bsh[2][BN * 32];
    constexpr int MR = BM / 32;
    constexpr int NR = BN / 32;
    constexpr int ROUNDS = (BM + BN) / 64;
    const int tid = threadIdx.x;
    const int lane = tid & 63, w = tid >> 6;
    const int wm = w >> 1, wn = w & 1;
    const int lr = lane & 15, lg = lane >> 4;
    const int seg = lane & 3;
    const long m0 = (long)blockIdx.y * BM, n0 = (long)blockIdx.x * BN;

    f32x4 acc[MR][NR];
#pragma unroll
    for (int i = 0; i < MR; i++)
#pragma unroll
        for (int j = 0; j < NR; j++) { f32x4 z = {0.f, 0.f, 0.f, 0.f}; acc[i][j] = z; }

    auto stage = [&](int buf, int kk) {
        const long k0 = (long)kk * 32;
#pragma unroll
        for (int rd = 0; rd < ROUNDS; rd++) {
            const int rbase = rd * 64 + w * 16;       // wave-uniform
            const int r = rbase + (lane >> 2);        // per-lane source row
            if (rbase < BM) {
                __builtin_amdgcn_global_load_lds(
                    (const AS1 void*)(A + (m0 + r) * K + k0 + seg * 8),
                    (AS3 void*)(&Ash[buf][rbase * 32]), 16, 0, 0);
            } else {
                __builtin_amdgcn_global_load_lds(
                    (const AS1 void*)(BT + (n0 + r - BM) * K + k0 + seg * 8),
                    (AS3 void*)(&Bsh[buf][(rbase - BM) * 32]), 16, 0, 0);
            }
        }
    };

    const int ksteps = K >> 5;
    stage(0, 0);
    __syncthreads();
    int cur = 0;
    for (int kk = 0; kk < ksteps; ++kk) {
        if (kk + 1 < ksteps) stage(cur ^ 1, kk + 1);  // loads fly during MFMA
        s16x8 af[MR], bf[NR];
#pragma unroll
        for (int mi = 0; mi < MR; mi++)
            af[mi] = *(const s16x8*)&Ash[cur][(wm * (BM / 2) + mi * 16 + lr) * 32 + lg * 8];
#pragma unroll
        for (int ni = 0; ni < NR; ni++)
            bf[ni] = *(const s16x8*)&Bsh[cur][(wn * (BN / 2) + ni * 16 + lr) * 32 + lg * 8];
#pragma unroll
        for (int mi = 0; mi < MR; mi++)
#pragma unroll
            for (int ni = 0; ni < NR; ni++)
                acc[mi][ni] = __builtin_amdgcn_mfma_f32_16x16x32_bf16(af[mi], bf[ni], acc[mi][ni], 0, 0, 0);
        __syncthreads();
        cur ^= 1;
    }
    // epilogue: D layout: m = 4*(lane>>4)+reg, n = lane&15
#pragma unroll
    for (int mi = 0; mi < MR; mi++) {
#pragma unroll
        for (int ni = 0; ni < NR; ni++) {
#pragma unroll
            for (int r = 0; r < 4; r++) {
                long gm = m0 + wm * (BM / 2) + mi * 16 + lg * 4 + r;
                long gn = n0 + wn * (BN / 2) + ni * 16 + lr;
                float v = acc[mi][ni][r];
                if constexpr (EPI == 1) {
                    v += bias[gn];
                    v = 0.5f * v * (1.f + erff(v * 0.70710678118654752f));
                    ((u16*)Outv)[gm * (long)N + gn] = f2bf(v);
                } else if constexpr (EPI == 2) {
                    if (bias) v += bias[gn];
                    v += res[gm * (long)N + gn];
                    ((float*)Outv)[gm * (long)N + gn] = v;
                } else if constexpr (EPI == 3) {
                    ((u16*)Outv)[gm * (long)N + gn] = f2bf(v * QSCALE);
                } else if constexpr (EPI == 4) {
                    if (gn < 512) ((u16*)Outv)[gm * 512 + gn] = f2bf(v * QSCALE);
                    else          ((u16*)Outv2)[gm * 512 + (gn - 512)] = f2bf(v);
                } else {
                    ((u16*)Outv)[gm * (long)N + gn] = f2bf(v);
                }
            }
        }
    }
}

// ---------------------------------------------------------------------------
// Gated flash attention v6: LDS-staged K/V shared by 4 waves, double-
// buffered (stage-before-compute, 1 barrier/step), KV-split z=2.
// K tile [32][64] staged with inverse-swizzled SOURCE (chunk p holds
// logical chunk p^(row&7)) so swizzled ds_reads are conflict-free.
// V^T tile [64][32] linear (2-way = free). Fixed-max softmax, exp2 path.
// Writes unnormalized bf16 O-part + psum; combine kernel finishes.
// ---------------------------------------------------------------------------
__global__ __launch_bounds__(256)
void attn_gated6(const u16* __restrict__ Q, const u16* __restrict__ Kp,
                 const u16* __restrict__ VT, u16* __restrict__ OP,
                 float* __restrict__ PS, int Lq, int Lk, int Tk, int TT) {
    __shared__ u16 Kt[2][2048];   // [32 kv][64 d] (source-swizzled)
    __shared__ u16 Vt[2][2048];   // [64 d][32 kv]
    __shared__ u16 Psh[4][2][640];
    const int tid = threadIdx.x, lane = tid & 63, w = tid >> 6;
    const int lr = lane & 15, lg = lane >> 4;

    // bijective XCD swizzle on flat block id (nwg % 8 == 0)
    const int nx = gridDim.x, ny = gridDim.y;
    int id = blockIdx.x + nx * (blockIdx.y + ny * blockIdx.z);
    int qq = (nx * ny * gridDim.z) >> 3;
    int r2 = (id & 7) * qq + (id >> 3);
    int bx = r2 % nx; int t1 = r2 / nx; int by = t1 % ny; int bz = t1 / ny;

    const int b = by >> 3, h = by & 7;
    const long qrow0 = (long)b * Lq + (long)bx * 128 + w * 32;
    const int hoff = h * 64;
    const int Lkh = Lk >> 1;

    s16x8 qf[2][2];
#pragma unroll
    for (int s = 0; s < 2; s++)
#pragma unroll
        for (int dc = 0; dc < 2; dc++)
            qf[s][dc] = *(const s16x8*)&Q[(qrow0 + s * 16 + lr) * 512 + hoff + dc * 32 + lg * 8];

    f32x4 o[2][4];
#pragma unroll
    for (int s = 0; s < 2; s++)
#pragma unroll
        for (int dt = 0; dt < 4; dt++) { f32x4 z = {0.f, 0.f, 0.f, 0.f}; o[s][dt] = z; }
    float psum[2] = {0.f, 0.f};

    // staging sources (per-thread one 16B chunk of K and of V per step)
    const int krow = tid >> 3, kp = tid & 7;
    const u16* ksrc = Kp + ((long)b * Lk + (long)bz * Lkh + krow) * 512
                         + hoff + ((kp ^ (krow & 7)) * 8);
    const int vrow = tid >> 2, vc = tid & 3;
    const u16* vsrc = VT + (long)(hoff + vrow) * Tk + (long)b * Lk
                         + (long)bz * Lkh + vc * 8;

    auto stage = [&](int buf) {
        __builtin_amdgcn_global_load_lds((const AS1 void*)ksrc,
                                         (AS3 void*)(&Kt[buf][w * 512]), 16, 0, 0);
        __builtin_amdgcn_global_load_lds((const AS1 void*)vsrc,
                                         (AS3 void*)(&Vt[buf][w * 512]), 16, 0, 0);
        ksrc += 32 * 512;
        vsrc += 32;
    };

    const int steps = Lkh >> 5;
    stage(0);
    __syncthreads();
    int cur = 0;
    for (int it = 0; it < steps; ++it) {
        if (it + 1 < steps) stage(cur ^ 1);   // next tile flies during compute
        s16x8 kf[2][2], vb[4];
#pragma unroll
        for (int c = 0; c < 2; c++)
#pragma unroll
            for (int dc = 0; dc < 2; dc++)
                kf[c][dc] = *(const s16x8*)&Kt[cur][(c * 16 + lr) * 64 + (((dc * 4 + lg) ^ (lr & 7)) * 8)];
#pragma unroll
        for (int dt = 0; dt < 4; dt++)
            vb[dt] = *(const s16x8*)&Vt[cur][(dt * 16 + lr) * 32 + lg * 8];
#pragma unroll
        for (int s = 0; s < 2; s++) {
            f32x4 st[2];
            { f32x4 z = {0.f, 0.f, 0.f, 0.f}; st[0] = z; st[1] = z; }
#pragma unroll
            for (int c = 0; c < 2; c++)
#pragma unroll
                for (int dc = 0; dc < 2; dc++)
                    st[c] = __builtin_amdgcn_mfma_f32_16x16x32_bf16(kf[c][dc], qf[s][dc], st[c], 0, 0, 0);
            uint2 pk[2];
#pragma unroll
            for (int c = 0; c < 2; c++) {
                float e0 = EXP2(st[c][0]), e1 = EXP2(st[c][1]);
                float e2 = EXP2(st[c][2]), e3 = EXP2(st[c][3]);
                psum[s] += (e0 + e1) + (e2 + e3);
                float g0 = st[c][0] > 0.f ? e0 : 0.f;
                float g1 = st[c][1] > 0.f ? e1 : 0.f;
                float g2 = st[c][2] > 0.f ? e2 : 0.f;
                float g3 = st[c][3] > 0.f ? e3 : 0.f;
                pk[c].x = pack_bf2r(g0, g1);
                pk[c].y = pack_bf2r(g2, g3);
            }
            u16* psh = &Psh[w][s][0];
#pragma unroll
            for (int c = 0; c < 2; c++)
                *(uint2*)&psh[lr * 40 + c * 16 + lg * 4] = pk[c];
            s16x8 pa = *(const s16x8*)&psh[lr * 40 + lg * 8];
#pragma unroll
            for (int dt = 0; dt < 4; dt++)
                o[s][dt] = __builtin_amdgcn_mfma_f32_16x16x32_bf16(pa, vb[dt], o[s][dt], 0, 0, 0);
        }
        __syncthreads();   // drains staged loads; protects buf reuse
        cur ^= 1;
    }

    u16* op = OP + (long)bz * TT * 512;
    float* ps = PS + (long)bz * TT * 8;
#pragma unroll
    for (int s = 0; s < 2; s++) {
        float red = psum[s];
        red += __shfl_xor(red, 16);
        red += __shfl_xor(red, 32);
        if (lg == 0) ps[(qrow0 + s * 16 + lr) * 8 + h] = red;
#pragma unroll
        for (int dt = 0; dt < 4; dt++) {
            long ob = (qrow0 + s * 16) * 512 + hoff + dt * 16 + lr;
            op[ob + (long)(lg * 4 + 0) * 512] = f2bf(o[s][dt][0]);
            op[ob + (long)(lg * 4 + 1) * 512] = f2bf(o[s][dt][1]);
            op[ob + (long)(lg * 4 + 2) * 512] = f2bf(o[s][dt][2]);
            op[ob + (long)(lg * 4 + 3) * 512] = f2bf(o[s][dt][3]);
        }
    }
}

// combine: O = (P0 + P1) / (ps0 + ps1), 8 dims per thread
__global__ __launch_bounds__(256)
void attn_combine(const u16* __restrict__ OP, const float* __restrict__ PS,
                  u16* __restrict__ O, int TT) {
    long i = (long)blockIdx.x * 256 + threadIdx.x;
    long t = i >> 6; int g = (int)(i & 63); int d0 = g * 8; int h = g >> 3;
    float rinv = 1.f / (PS[t * 8 + h] + PS[(long)TT * 8 + t * 8 + h]);
    s16x8 va = *(const s16x8*)&OP[t * 512 + d0];
    s16x8 vb = *(const s16x8*)&OP[(long)TT * 512 + t * 512 + d0];
    s16x8 ov;
#pragma unroll
    for (int j = 0; j < 8; j++)
        ov[j] = (short)f2bf((bf2f((u16)va[j]) + bf2f((u16)vb[j])) * rinv);
    *(s16x8*)&O[t * 512 + d0] = ov;
}

// ---------------------------------------------------------------------------
extern "C" void kernel_launch(void* const* d_in, const int* in_sizes, int n_in,
                              void* d_out, int out_size, void* d_ws, size_t ws_size,
                              hipStream_t stream) {
    const float* X    = (const float*)d_in[0];   // [4,2048,512]
    const float* Z    = (const float*)d_in[1];   // [4,1024,100]
    const float* Wq_s = (const float*)d_in[2];
    const float* Wk_s = (const float*)d_in[3];
    const float* Wv_s = (const float*)d_in[4];
    const float* Wo_s = (const float*)d_in[5];
    const float* Wq_c = (const float*)d_in[6];
    const float* Wk_c = (const float*)d_in[7];   // [100,512]
    const float* Wv_c = (const float*)d_in[8];   // [100,512]
    const float* Wo_c = (const float*)d_in[9];
    const float* g1   = (const float*)d_in[10];
    const float* b1   = (const float*)d_in[11];
    const float* g2   = (const float*)d_in[12];
    const float* b2   = (const float*)d_in[13];
    const float* W1   = (const float*)d_in[14];
    const float* bf1  = (const float*)d_in[15];
    const float* W2   = (const float*)d_in[16];
    const float* bf2  = (const float*)d_in[17];
    float* out = (float*)d_out;
    const int TT = 8192;  // total token rows (4 * 2048)

    char* p = (char*)d_ws;
    auto take = [&](size_t n) { char* q = p; p += (n + 255) & ~(size_t)255; return q; };
    u16* WqkT = (u16*)take((size_t)2 * 512 * 512 * 2);  // WqsT | WksT contiguous
    u16* WqsT = WqkT;
    u16* WksT = WqkT + 512 * 512;
    u16* WvsT = (u16*)take(512 * 512 * 2);
    u16* WosT = (u16*)take(512 * 512 * 2);
    u16* WqcT = (u16*)take(512 * 512 * 2);
    u16* WocT = (u16*)take(512 * 512 * 2);
    u16* W1T  = (u16*)take(512 * 512 * 2);
    u16* W2T  = (u16*)take(512 * 512 * 2);
    u16* WkcT = (u16*)take(512 * 128 * 2);
    u16* WvcT = (u16*)take(512 * 128 * 2);
    u16* nbuf = (u16*)take((size_t)TT * 512 * 2);
    u16* qbuf = (u16*)take((size_t)TT * 512 * 2);
    u16* kbuf = (u16*)take((size_t)TT * 512 * 2);
    u16* vtbuf = (u16*)take((size_t)TT * 512 * 2);   // V^T [512][tokens]
    u16* abuf = (u16*)take((size_t)TT * 512 * 2);
    u16* znb  = (u16*)take((size_t)4096 * 128 * 2);
    u16* opart = (u16*)take((size_t)2 * TT * 512 * 2);  // unnormalized O halves
    float* psum = (float*)take((size_t)2 * TT * 8 * 4); // softmax denominators

    // weights -> bf16 transposed (2 batched launches)
    WPtrs w8{};
    w8.s[0] = Wq_s; w8.d[0] = WqsT;
    w8.s[1] = Wk_s; w8.d[1] = WksT;
    w8.s[2] = Wv_s; w8.d[2] = WvsT;
    w8.s[3] = Wo_s; w8.d[3] = WosT;
    w8.s[4] = Wq_c; w8.d[4] = WqcT;
    w8.s[5] = Wo_c; w8.d[5] = WocT;
    w8.s[6] = W1;   w8.d[6] = W1T;
    w8.s[7] = W2;   w8.d[7] = W2T;
    wt_batch<<<dim3(1024, 8), 256, 0, stream>>>(w8, 512, 512, 512);
    WPtrs w2{};
    w2.s[0] = Wk_c; w2.d[0] = WkcT;
    w2.s[1] = Wv_c; w2.d[1] = WvcT;
    wt_batch<<<dim3(256, 2), 256, 0, stream>>>(w2, 100, 512, 128);

    // stage 1: self attention (Q+K fused projection; V transposed via swap)
    ln512<<<2048, 256, 0, stream>>>(X, g1, b1, nbuf);
    gemm_p<128, 64, 4><<<dim3(16, 64), 256, 0, stream>>>(nbuf, WqkT, qbuf, kbuf, nullptr, nullptr, 8192, 1024, 512);
    gemm_p<64, 128, 0><<<dim3(64, 8), 256, 0, stream>>>(WvsT, nbuf, vtbuf, nullptr, nullptr, nullptr, 512, 8192, 512);
    attn_gated6<<<dim3(16, 32, 2), 256, 0, stream>>>(qbuf, kbuf, vtbuf, opart, psum, 2048, 2048, 8192, TT);
    attn_combine<<<2048, 256, 0, stream>>>(opart, psum, abuf, TT);
    gemm_p<128, 64, 2><<<dim3(8, 64), 256, 0, stream>>>(abuf, WosT, d_out, nullptr, nullptr, X, 8192, 512, 512);

    // stage 2: cross attention
    ln512<<<2048, 256, 0, stream>>>(out, g1, b1, nbuf);
    ln_z<<<1024, 256, 0, stream>>>(Z, g2, b2, znb);
    gemm_p<128, 64, 3><<<dim3(8, 64), 256, 0, stream>>>(nbuf, WqcT, qbuf, nullptr, nullptr, nullptr, 8192, 512, 512);
    gemm_p<128, 64, 0><<<dim3(8, 32), 256, 0, stream>>>(znb, WkcT, kbuf, nullptr, nullptr, nullptr, 4096, 512, 128);
    gemm_p<64, 128, 0><<<dim3(32, 8), 256, 0, stream>>>(WvcT, znb, vtbuf, nullptr, nullptr, nullptr, 512, 4096, 128);
    attn_gated6<<<dim3(16, 32, 2), 256, 0, stream>>>(qbuf, kbuf, vtbuf, opart, psum, 2048, 1024, 4096, TT);
    attn_combine<<<2048, 256, 0, stream>>>(opart, psum, abuf, TT);
    gemm_p<128, 64, 2><<<dim3(8, 64), 256, 0, stream>>>(abuf, WocT, d_out, nullptr, nullptr, out, 8192, 512, 512);

    // stage 3: FFN
    ln512<<<2048, 256, 0, stream>>>(out, g1, b1, nbuf);
    gemm_p<128, 64, 1><<<dim3(8, 64), 256, 0, stream>>>(nbuf, W1T, abuf, nullptr, bf1, nullptr, 8192, 512, 512);
    gemm_p<128, 64, 2><<<dim3(8, 64), 256, 0, stream>>>(abuf, W2T, d_out, nullptr, bf2, out, 8192, 512, 512);
}